// Round 15
// baseline (340.138 us; speedup 1.0000x reference)
//
#include <hip/hip_runtime.h>

typedef __attribute__((ext_vector_type(8))) short short8;
typedef __attribute__((ext_vector_type(4))) float f32x4;
typedef __attribute__((ext_vector_type(4))) unsigned short ushort4v;
typedef __attribute__((ext_vector_type(8))) unsigned short ushort8v;
typedef unsigned short ushortT;

#define PADROWS 4098
#define HSTR 2056
#define PI_F 3.14159265358979323f
#define PHYS(i) ((i) ^ (((i) >> 4) & 15))

__device__ __forceinline__ ushortT f2bf(float f) {
  union { float f; unsigned int u; } v; v.f = f;
  unsigned int r = (v.u + 0x7FFFu + ((v.u >> 16) & 1u)) >> 16;
  return (ushortT)r;
}
__device__ __forceinline__ float bf2f(ushortT b) {
  union { unsigned int u; float f; } v; v.u = ((unsigned int)b) << 16;
  return v.f;
}

__device__ __forceinline__ void gl2lds16(const void* g, void* l) {
  __builtin_amdgcn_global_load_lds((const __attribute__((address_space(1))) void*)g,
                                   (__attribute__((address_space(3))) void*)l, 16, 0, 0);
}

// ---------------- fused prep: u->Upad(+pad), pW cast, tables, cW->Wt + pbC ----------------

__global__ void prep_cwt(const float* __restrict__ u, ushortT* __restrict__ up,
                         const float* __restrict__ pW, ushortT* __restrict__ pW_bf,
                         float2* __restrict__ Wg, float2* __restrict__ Sg,
                         const float* __restrict__ cW, const float* __restrict__ pb,
                         const float* __restrict__ cb, ushortT* __restrict__ Wt,
                         float* __restrict__ biasC, float* __restrict__ pbC0,
                         float* __restrict__ pbC2) {
  int blk = blockIdx.x;
  int tid = threadIdx.x;
  if (blk < 8192) {
    size_t idx = (size_t)blk * 256 + tid;
    f32x4 v = *(const f32x4*)(u + idx * 4);
    ushort4v r;
    r[0] = f2bf(v[0]); r[1] = f2bf(v[1]); r[2] = f2bf(v[2]); r[3] = f2bf(v[3]);
    size_t g = idx * 4;
    int col = (int)(g & 511);
    int l = (int)(g >> 9);
    int b = l >> 12;
    *(ushort4v*)(up + ((size_t)b * PADROWS + (l & 4095) + 1) * 512 + col) = r;
    return;
  }
  if (blk < 8208) {
    int idx = (blk - 8192) * 256 + tid;   // 4096
    int col = idx & 511;
    int r = (idx >> 9) & 1;
    int b = idx >> 10;
    up[((size_t)b * PADROWS + (r ? 4097 : 0)) * 512 + col] = 0;
    return;
  }
  if (blk < 9232) {
    size_t idx = (size_t)(blk - 8208) * 256 + tid;
    f32x4 v = *(const f32x4*)(pW + idx * 4);
    ushort4v r;
    r[0] = f2bf(v[0]); r[1] = f2bf(v[1]); r[2] = f2bf(v[2]); r[3] = f2bf(v[3]);
    *(ushort4v*)(pW_bf + idx * 4) = r;
    return;
  }
  if (blk < 9244) {
    int m = (blk - 9232) * 256 + tid;  // 3072
    float sn, cs;
    if (m < 2048) {
      sincosf(-2.0f * PI_F * (float)m / 2048.0f, &sn, &cs);
      Wg[m] = make_float2(cs, sn);
    } else {
      int k = m - 2048;
      sincosf(PI_F * (float)k / 2048.0f, &sn, &cs);
      Sg[k] = make_float2(cs, sn);
    }
    return;
  }
  // cW pass: o = blk - 9244 (2048 blocks)
  int o = blk - 9244;
  float s0 = 0.f, s1 = 0.f, s2 = 0.f;
  const float* base = cW + (size_t)o * 6144;
  for (int i = tid; i < 2048; i += 256) {
    float w0 = base[i * 3], w1 = base[i * 3 + 1], w2 = base[i * 3 + 2];
    size_t oi = (size_t)o * 2048 + i;
    Wt[oi]           = f2bf(w0);
    Wt[oi + 4194304] = f2bf(w1);
    Wt[oi + 8388608] = f2bf(w2);
    float p = pb[i];
    s0 = fmaf(p, w0, s0);
    s1 = fmaf(p, w1, s1);
    s2 = fmaf(p, w2, s2);
  }
#pragma unroll
  for (int off = 32; off >= 1; off >>= 1) {
    s0 += __shfl_down(s0, off);
    s1 += __shfl_down(s1, off);
    s2 += __shfl_down(s2, off);
  }
  __shared__ float red[4][3];
  if ((tid & 63) == 0) { red[tid >> 6][0] = s0; red[tid >> 6][1] = s1; red[tid >> 6][2] = s2; }
  __syncthreads();
  if (tid == 0) {
    float a0 = red[0][0] + red[1][0] + red[2][0] + red[3][0];
    float a1 = red[0][1] + red[1][1] + red[2][1] + red[3][1];
    float a2 = red[0][2] + red[1][2] + red[2][2] + red[3][2];
    biasC[o] = cb[o] + a0 + a1 + a2;
    pbC0[o] = a0;
    pbC2[o] = a2;
  }
}

// ---------------- fold GEMM: cWf[h][o][j] = sum_i Wt[h][o][i] * pW[j][i] ----------------
// 64(o) x 128(j) tile, grid (32,4,3) = 384 blocks, 24 KiB LDS.

__launch_bounds__(256, 4)
__global__ void gemm_fold(const ushortT* __restrict__ Wt, const ushortT* __restrict__ pW_bf,
                          ushortT* __restrict__ cWf) {
  __shared__ alignas(16) ushortT As[64 * 64];    // 8 KiB
  __shared__ alignas(16) ushortT Bs[128 * 64];   // 16 KiB
  const int tid = threadIdx.x;
  const int lane = tid & 63, w = tid >> 6;
  const int wm = w >> 1, wn = w & 1;
  const int tm = blockIdx.x, tn = blockIdx.y, h = blockIdx.z;
  const ushortT* A = Wt + (size_t)h * 4194304;
  f32x4 acc[2][4] = {};
#pragma unroll 1
  for (int kt = 0; kt < 32; ++kt) {
    const int i0 = kt * 64;
#pragma unroll
    for (int i = 0; i < 2; ++i) {
      int ldsoff = (i * 4 + w) * 1024;
      int m = ((i * 4 + w) << 3) + (lane >> 3);   // 0..63
      int col = (lane & 7) * 8;
      gl2lds16(A + (size_t)(tm * 64 + m) * 2048 + i0 + col, (char*)As + ldsoff);
    }
#pragma unroll
    for (int i = 0; i < 4; ++i) {
      int ldsoff = (i * 4 + w) * 1024;
      int m = ((i * 4 + w) << 3) + (lane >> 3);   // 0..127
      int col = (lane & 7) * 8;
      gl2lds16(pW_bf + (size_t)(tn * 128 + m) * 2048 + i0 + col, (char*)Bs + ldsoff);
    }
    __syncthreads();
#pragma unroll
    for (int ks = 0; ks < 2; ++ks) {
      short8 av[2], bv[4];
#pragma unroll
      for (int mi = 0; mi < 2; ++mi) {
        int row = wm * 32 + mi * 16 + (lane & 15);
        av[mi] = *(const short8*)(As + row * 64 + (ks * 4 + (lane >> 4)) * 8);
      }
#pragma unroll
      for (int ni = 0; ni < 4; ++ni) {
        int row = wn * 64 + ni * 16 + (lane & 15);
        bv[ni] = *(const short8*)(Bs + row * 64 + (ks * 4 + (lane >> 4)) * 8);
      }
#pragma unroll
      for (int mi = 0; mi < 2; ++mi)
#pragma unroll
        for (int ni = 0; ni < 4; ++ni)
          acc[mi][ni] = __builtin_amdgcn_mfma_f32_16x16x32_bf16(av[mi], bv[ni], acc[mi][ni], 0, 0, 0);
    }
    __syncthreads();
  }
#pragma unroll
  for (int mi = 0; mi < 2; ++mi)
#pragma unroll
    for (int ni = 0; ni < 4; ++ni) {
      int jc = tn * 128 + wn * 64 + ni * 16 + (lane & 15);
#pragma unroll
      for (int j = 0; j < 4; ++j) {
        int o = tm * 64 + wm * 32 + mi * 16 + (lane >> 4) * 4 + j;
        cWf[((size_t)h * 2048 + o) * 512 + jc] = f2bf(acc[mi][ni][j]);
      }
    }
}

// ---------------- conv GEMM: 256x256, BK=64, 8-phase SINGLE-BARRIER pipeline ----------------

__launch_bounds__(512, 2)
__global__ void gemm_conv8(const ushortT* __restrict__ Upad, const ushortT* __restrict__ cWf,
                           const float* __restrict__ biasC, const float* __restrict__ pbC0,
                           const float* __restrict__ pbC2, ushortT* __restrict__ vTb,
                           ushortT* __restrict__ projsT) {
  __shared__ ushortT lds[2][2][16384];
  const int tid = threadIdx.x;
  const int lane = tid & 63, w = tid >> 6;
  const int wm = w >> 2, wn = w & 3;
  int raw = blockIdx.x;
  int wg  = (raw & 7) * 64 + (raw >> 3);
  const int o0 = (wg >> 6) << 8;
  const int nt = wg & 63;
  const int b  = nt >> 4;
  const int l0 = (nt & 15) << 8;

  f32x4 acc[8][4] = {};
  short8 xf[4][2];

  const int sm = tid >> 3;
  const int sw1 = ((tid & 7) ^ (sm & 7)) << 3;

  auto stageW = [&](int slot, int half, int t) {
    int q = (t * 21846) >> 16, h = t - 3 * q, j0 = q << 6;
    size_t grow = (size_t)(h * 2048 + o0 + half * 128 + sm);
    char* dst = (char*)&lds[slot][0][0] + half * 16384 + w * 1024;
    gl2lds16(cWf + grow * 512 + j0 + sw1, dst);
    gl2lds16(cWf + (grow + 64) * 512 + j0 + sw1, dst + 8192);
  };
  auto stageX = [&](int slot, int half, int t) {
    int q = (t * 21846) >> 16, h = t - 3 * q, j0 = q << 6;
    size_t grow = (size_t)b * PADROWS + l0 + h + half * 128 + sm;
    char* dst = (char*)&lds[slot][1][0] + half * 16384 + w * 1024;
    gl2lds16(Upad + grow * 512 + j0 + sw1, dst);
    gl2lds16(Upad + (grow + 64) * 512 + j0 + sw1, dst + 8192);
  };
  auto ldsW = [&](int slot, int mi, int ks) -> short8 {
    int row = wm * 128 + mi * 16 + (lane & 15);
    int ch = (ks * 4 + (lane >> 4)) ^ (row & 7);
    return *(const short8*)&lds[slot][0][row * 64 + ch * 8];
  };
  auto ldsX = [&](int slot, int ni, int ks) -> short8 {
    int row = wn * 64 + ni * 16 + (lane & 15);
    int ch = (ks * 4 + (lane >> 4)) ^ (row & 7);
    return *(const short8*)&lds[slot][1][row * 64 + ch * 8];
  };

  stageW(0, 0, 0); stageW(0, 1, 0);
  stageX(0, 0, 0); stageX(0, 1, 0);
  stageX(1, 0, 1); stageX(1, 1, 1);
  asm volatile("s_waitcnt vmcnt(0)" ::: "memory");
  __builtin_amdgcn_s_barrier();

#define PHASE(slot, q, STAGECODE, VMCODE)                                                                    \
  {                                                                                                          \
    short8 w0k0 = ldsW(slot, 2*(q), 0), w0k1 = ldsW(slot, 2*(q), 1);                                         \
    short8 w1k0 = ldsW(slot, 2*(q)+1, 0), w1k1 = ldsW(slot, 2*(q)+1, 1);                                     \
    if ((q) == 0) {                                                                                          \
      _Pragma("unroll")                                                                                      \
      for (int ni = 0; ni < 4; ++ni) {                                                                       \
        xf[ni][0] = ldsX(slot, ni, 0);                                                                       \
        xf[ni][1] = ldsX(slot, ni, 1);                                                                       \
      }                                                                                                      \
    }                                                                                                        \
    STAGECODE;                                                                                               \
    VMCODE;                                                                                                  \
    __builtin_amdgcn_s_barrier();                                                                            \
    asm volatile("s_waitcnt lgkmcnt(0)" ::: "memory");                                                       \
    __builtin_amdgcn_sched_barrier(0);                                                                       \
    __builtin_amdgcn_s_setprio(1);                                                                           \
    _Pragma("unroll")                                                                                        \
    for (int ni = 0; ni < 4; ++ni) {                                                                         \
      acc[2*(q)][ni]   = __builtin_amdgcn_mfma_f32_16x16x32_bf16(w0k0, xf[ni][0], acc[2*(q)][ni], 0, 0, 0);  \
      acc[2*(q)][ni]   = __builtin_amdgcn_mfma_f32_16x16x32_bf16(w0k1, xf[ni][1], acc[2*(q)][ni], 0, 0, 0);  \
      acc[2*(q)+1][ni] = __builtin_amdgcn_mfma_f32_16x16x32_bf16(w1k0, xf[ni][0], acc[2*(q)+1][ni], 0, 0, 0);\
      acc[2*(q)+1][ni] = __builtin_amdgcn_mfma_f32_16x16x32_bf16(w1k1, xf[ni][1], acc[2*(q)+1][ni], 0, 0, 0);\
    }                                                                                                        \
    __builtin_amdgcn_s_setprio(0);                                                                           \
  }

#pragma unroll 1
  for (int it = 0; it < 11; ++it) {
    const int t0 = 2 * it;
    PHASE(0, 0, , );
    PHASE(0, 1, stageW(1, 0, t0 + 1), );
    PHASE(0, 2, stageW(1, 1, t0 + 1); stageX(0, 0, t0 + 2), );
    PHASE(0, 3, stageX(0, 1, t0 + 2), asm volatile("s_waitcnt vmcnt(4)" ::: "memory"));
    PHASE(1, 0, , );
    PHASE(1, 1, stageW(0, 0, t0 + 2), );
    PHASE(1, 2, stageW(0, 1, t0 + 2); stageX(1, 0, t0 + 3), );
    PHASE(1, 3, stageX(1, 1, t0 + 3), asm volatile("s_waitcnt vmcnt(4)" ::: "memory"));
  }
  // peel: t=22 (slot0), t=23 (slot1); only W(23) still needs staging
  PHASE(0, 0, , );
  PHASE(0, 1, stageW(1, 0, 23), );
  PHASE(0, 2, stageW(1, 1, 23), );
  PHASE(0, 3, , asm volatile("s_waitcnt vmcnt(0)" ::: "memory"));
  PHASE(1, 0, , );
  PHASE(1, 1, , );
  PHASE(1, 2, , );
  PHASE(1, 3, , );
#undef PHASE

  const int r4 = (lane >> 4) * 4;
  const int lbase = l0 + wn * 64 + (lane & 15);
  if (o0 < 512) {
#pragma unroll
    for (int mi = 0; mi < 8; ++mi)
#pragma unroll
      for (int ni = 0; ni < 4; ++ni) {
        int l = lbase + ni * 16;
#pragma unroll
        for (int j = 0; j < 4; ++j) {
          int o = o0 + wm * 128 + mi * 16 + r4 + j;
          float val = acc[mi][ni][j] + biasC[o];
          if (l == 0) val -= pbC0[o];
          if (l == 4095) val -= pbC2[o];
          vTb[((size_t)b * 512 + o) * 4096 + l] = f2bf(val);
        }
      }
  } else {
#pragma unroll
    for (int mi = 0; mi < 8; ++mi)
#pragma unroll
      for (int ni = 0; ni < 4; ++ni) {
        int l = lbase + ni * 16;
#pragma unroll
        for (int j = 0; j < 4; ++j) {
          int o = o0 + wm * 128 + mi * 16 + r4 + j;
          float val = acc[mi][ni][j] + biasC[o];
          if (l == 0) val -= pbC0[o];
          if (l == 4095) val -= pbC2[o];
          int oc = o - 512;
          projsT[((size_t)((oc >> 9) * 4 + b) * 512 + (oc & 511)) * 4096 + l] = f2bf(val);
        }
      }
  }
}

// ---------------- filter GEMM: hT[ch][l] = (t @ fW + fb)*window, PE computed in-kernel ----------------

__launch_bounds__(256, 1)
__global__ void h_kernel(const float* __restrict__ fW, const float* __restrict__ fb,
                         float* __restrict__ hT) {
  __shared__ float tTs[128][64];
  __shared__ float fWs[128][128];
  const int l0 = blockIdx.x * 64;
  const int c0 = blockIdx.y * 128;
  const int tid = threadIdx.x;
  for (int r = tid; r < 4096; r += 256) {
    int d2 = r >> 6, li = r & 63;
    float dv = expf(-9.210340371976184f * (float)(2 * d2) / 128.0f);
    float ang = (float)(l0 + li) * dv;
    tTs[2 * d2][li] = sinf(ang);
    tTs[2 * d2 + 1][li] = cosf(ang);
  }
  {
    int cq = (tid & 31) * 4;
    int dr = tid >> 5;
#pragma unroll
    for (int d = dr; d < 128; d += 8)
      *(f32x4*)(&fWs[d][cq]) = *(const f32x4*)(fW + (size_t)d * 1536 + c0 + cq);
  }
  __syncthreads();
  const int lgrp = tid & 15;
  const int cg = tid >> 4;
  float acc[8][4] = {};
#pragma unroll 4
  for (int d = 0; d < 128; ++d) {
    f32x4 tv = *(const f32x4*)(&tTs[d][lgrp * 4]);
#pragma unroll
    for (int j = 0; j < 8; ++j) {
      float wv = fWs[d][cg + 16 * j];
      acc[j][0] = fmaf(tv[0], wv, acc[j][0]);
      acc[j][1] = fmaf(tv[1], wv, acc[j][1]);
      acc[j][2] = fmaf(tv[2], wv, acc[j][2]);
      acc[j][3] = fmaf(tv[3], wv, acc[j][3]);
    }
  }
  f32x4 wl;
#pragma unroll
  for (int j = 0; j < 4; ++j) {
    int l = l0 + lgrp * 4 + j;
    wl[j] = 0.5f * (1.0f - cosf(6.283185307179586f * (float)l / 4095.0f));
  }
#pragma unroll
  for (int j = 0; j < 8; ++j) {
    int ch = c0 + cg + 16 * j;
    float fbv = fb[ch];
    f32x4 r;
    r[0] = (acc[j][0] + fbv) * wl[0];
    r[1] = (acc[j][1] + fbv) * wl[1];
    r[2] = (acc[j][2] + fbv) * wl[2];
    r[3] = (acc[j][3] + fbv) * wl[3];
    *(f32x4*)(hT + (size_t)ch * 4096 + l0 + lgrp * 4) = r;
  }
}

// ---------------- radix-8 Stockham FFT, N=2048 complex, in-place in LDS ----------------
// Twiddle table halved: Wl[1024] holds exp(-2*pi*i*m/2048) for m<1024; W[m+1024] = -W[m].

__device__ __forceinline__ float2 cadd(float2 a, float2 b){ return make_float2(a.x+b.x, a.y+b.y); }
__device__ __forceinline__ float2 csub(float2 a, float2 b){ return make_float2(a.x-b.x, a.y-b.y); }
__device__ __forceinline__ float2 cmulp(float2 a, float2 b){
  return make_float2(a.x*b.x - a.y*b.y, a.x*b.y + a.y*b.x);
}
__device__ __forceinline__ float2 ldw(const float2* __restrict__ Wl, int m) {
  float2 w = Wl[PHYS(m & 1023)];
  unsigned int neg = (unsigned int)(m & 1024) << 21;   // 0x80000000 when m>=1024
  w.x = __uint_as_float(__float_as_uint(w.x) ^ neg);
  w.y = __uint_as_float(__float_as_uint(w.y) ^ neg);
  return w;
}
template<bool INV>
__device__ __forceinline__ float2 tw_mul(float2 a, float2 w) {
  return INV ? make_float2(fmaf(a.x, w.x,  a.y*w.y), fmaf(a.y, w.x, -a.x*w.y))
             : make_float2(fmaf(a.x, w.x, -a.y*w.y), fmaf(a.x, w.y,  a.y*w.x));
}
template<bool INV>
__device__ __forceinline__ float2 rot(float2 z) {
  return INV ? make_float2(-z.y, z.x) : make_float2(z.y, -z.x);
}

template<bool INV>
__device__ __forceinline__ void bfly8(const float2 v[8], float2 o[8]) {
  const float C7 = 0.70710678118654752f;
  float2 a0 = cadd(v[0], v[4]), a1 = csub(v[0], v[4]);
  float2 a2 = cadd(v[2], v[6]), a3 = rot<INV>(csub(v[2], v[6]));
  float2 E0 = cadd(a0, a2), E1 = cadd(a1, a3), E2 = csub(a0, a2), E3 = csub(a1, a3);
  float2 b0 = cadd(v[1], v[5]), b1 = csub(v[1], v[5]);
  float2 b2 = cadd(v[3], v[7]), b3 = rot<INV>(csub(v[3], v[7]));
  float2 O0 = cadd(b0, b2), O1 = cadd(b1, b3), O2 = csub(b0, b2), O3 = csub(b1, b3);
  O1 = cmulp(O1, INV ? make_float2(C7, C7) : make_float2(C7, -C7));
  O2 = rot<INV>(O2);
  O3 = cmulp(O3, INV ? make_float2(-C7, C7) : make_float2(-C7, -C7));
  o[0] = cadd(E0, O0); o[1] = cadd(E1, O1); o[2] = cadd(E2, O2); o[3] = cadd(E3, O3);
  o[4] = csub(E0, O0); o[5] = csub(E1, O1); o[6] = csub(E2, O2); o[7] = csub(E3, O3);
}

template<bool INV, int NS>
__device__ __forceinline__ void stage_r8(float2* X, const float2* Wl, int t) {
  float2 v[8];
#pragma unroll
  for (int r = 0; r < 8; ++r) v[r] = X[PHYS(t + 256 * r)];
  if (NS > 1) {
    const int jm = (t & (NS - 1)) * (256 / NS);
#pragma unroll
    for (int r = 1; r < 8; ++r) v[r] = tw_mul<INV>(v[r], ldw(Wl, r * jm));
  }
  float2 o[8];
  bfly8<INV>(v, o);
  __syncthreads();
  const int base = (t / NS) * (8 * NS) + (t % NS);
#pragma unroll
  for (int i = 0; i < 8; ++i) X[PHYS(base + i * NS)] = o[i];
  __syncthreads();
}

template<bool INV>
__device__ __forceinline__ void stage_r4(float2* X, const float2* Wl, int t) {
#pragma unroll
  for (int jj = 0; jj < 2; ++jj) {
    const int j = t + jj * 256;
    float2 v0 = X[PHYS(j)], v1 = X[PHYS(j + 512)], v2 = X[PHYS(j + 1024)], v3 = X[PHYS(j + 1536)];
    v1 = tw_mul<INV>(v1, ldw(Wl, j));
    v2 = tw_mul<INV>(v2, ldw(Wl, 2 * j));
    v3 = tw_mul<INV>(v3, ldw(Wl, 3 * j));
    float2 a0 = cadd(v0, v2), a1 = csub(v0, v2), a2 = cadd(v1, v3), a3 = rot<INV>(csub(v1, v3));
    X[PHYS(j)]        = cadd(a0, a2);
    X[PHYS(j + 512)]  = cadd(a1, a3);
    X[PHYS(j + 1024)] = csub(a0, a2);
    X[PHYS(j + 1536)] = csub(a1, a3);
  }
  __syncthreads();
}

__device__ __forceinline__ void fwd_stage1_bf16(float2* X, const unsigned int* __restrict__ sigb, int t) {
  float2 v[8], o[8];
#pragma unroll
  for (int r = 0; r < 8; ++r) {
    unsigned int pr = sigb[t + 256 * r];
    v[r] = make_float2(bf2f((ushortT)(pr & 0xffffu)), bf2f((ushortT)(pr >> 16)));
  }
  bfly8<false>(v, o);
  const int base = t * 8;
#pragma unroll
  for (int i = 0; i < 8; ++i) X[PHYS(base + i)] = o[i];
  __syncthreads();
}

__device__ __forceinline__ void fwd_stage1_f32(float2* X, const float* __restrict__ sig, int t) {
  float2 v[8], o[8];
#pragma unroll
  for (int r = 0; r < 8; ++r) v[r] = *(const float2*)(sig + 2 * (t + 256 * r));
  bfly8<false>(v, o);
  const int base = t * 8;
#pragma unroll
  for (int i = 0; i < 8; ++i) X[PHYS(base + i)] = o[i];
  __syncthreads();
}

__device__ __forceinline__ void fwd_stage1_gated(float2* X, const unsigned int* __restrict__ xnb,
                                                 float scale, int t) {
  float2 v[8], o[8];
#pragma unroll
  for (int r = 0; r < 8; ++r) {
    const int m = t + 256 * r;
    unsigned int pr = xnb[m];
    float2 a = X[PHYS(m)];
    v[r] = make_float2(a.x * scale * bf2f((ushortT)(pr & 0xffffu)),
                       a.y * scale * bf2f((ushortT)(pr >> 16)));
  }
  bfly8<false>(v, o);
  __syncthreads();
  const int base = t * 8;
#pragma unroll
  for (int i = 0; i < 8; ++i) X[PHYS(base + i)] = o[i];
  __syncthreads();
}

__device__ __forceinline__ void stage_r4_store(const float2* X, const float2* Wl,
                                               const unsigned int* __restrict__ xnb,
                                               float scale, unsigned int* __restrict__ outb, int t) {
#pragma unroll
  for (int jj = 0; jj < 2; ++jj) {
    const int j = t + jj * 256;
    float2 v0 = X[PHYS(j)], v1 = X[PHYS(j + 512)], v2 = X[PHYS(j + 1024)], v3 = X[PHYS(j + 1536)];
    v1 = tw_mul<true>(v1, ldw(Wl, j));
    v2 = tw_mul<true>(v2, ldw(Wl, 2 * j));
    v3 = tw_mul<true>(v3, ldw(Wl, 3 * j));
    float2 a0 = cadd(v0, v2), a1 = csub(v0, v2), a2 = cadd(v1, v3), a3 = rot<true>(csub(v1, v3));
    float2 y[4] = { cadd(a0, a2), cadd(a1, a3), csub(a0, a2), csub(a1, a3) };
    const int idx[4] = { j, j + 512, j + 1024, j + 1536 };
#pragma unroll
    for (int q = 0; q < 4; ++q) {
      unsigned int pr = xnb[idx[q]];
      unsigned int lo = f2bf(y[q].x * scale * bf2f((ushortT)(pr & 0xffffu)));
      unsigned int hi = f2bf(y[q].y * scale * bf2f((ushortT)(pr >> 16)));
      outb[idx[q]] = lo | (hi << 16);
    }
  }
}

// filters: rfft of hT rows -> half-spectrum Hf[ch][0..2048]
__launch_bounds__(256, 4)
__global__ void fft_filter_r(const float* __restrict__ hT, const float2* __restrict__ Wg,
                             float2* __restrict__ Hf) {
  __shared__ float2 X[2048];
  __shared__ float2 Wl[1024];
  const int ch = blockIdx.x;
  const int tid = threadIdx.x;
  const float* sig = hT + (size_t)ch * 4096;
  for (int m = tid; m < 1024; m += 256) Wl[PHYS(m)] = Wg[m];
  fwd_stage1_f32(X, sig, tid);
  stage_r8<false, 8>(X, Wl, tid);
  stage_r8<false, 64>(X, Wl, tid);
  stage_r4<false>(X, Wl, tid);
  float2* o = Hf + (size_t)ch * HSTR;
  for (int kk = tid; kk < 1024; kk += 256) {
    if (kk == 0) {
      float2 z0 = X[PHYS(0)];
      o[0]    = make_float2(z0.x + z0.y, 0.f);
      o[2048] = make_float2(z0.x - z0.y, 0.f);
      float2 zq = X[PHYS(1024)];
      o[1024] = make_float2(zq.x, -zq.y);
    } else {
      float2 zk = X[PHYS(kk)], zm = X[PHYS(2048 - kk)];
      float2 E = make_float2(0.5f * (zk.x + zm.x), 0.5f * (zk.y - zm.y));
      float2 D = make_float2(0.5f * (zk.x - zm.x), 0.5f * (zk.y + zm.y));
      float2 O = make_float2(D.y, -D.x);
      float sn, cs;
      __sincosf(-PI_F * (float)kk * (1.0f / 2048.0f), &sn, &cs);
      float2 twO = make_float2(O.x * cs - O.y * sn, O.x * sn + O.y * cs);
      o[kk]        = make_float2(E.x + twO.x, E.y + twO.y);
      o[2048 - kk] = make_float2(E.x - twO.x, -(E.y - twO.y));
    }
  }
}

// all 3 Hyena orders fused; TWO signals per block (512 thr), shared twiddle/S tables.
__launch_bounds__(512, 2)
__global__ void fft_conv3(ushortT* __restrict__ vTb, const ushortT* __restrict__ projsT,
                          const float2* __restrict__ Hf, const float2* __restrict__ Wg,
                          const float2* __restrict__ Sg) {
  __shared__ float2 X2[2][2048];
  __shared__ float2 Wl[1024];
  __shared__ float2 S[1024];
  const int tid = threadIdx.x;
  const int sig = tid >> 8;          // 0 or 1
  const int t = tid & 255;           // per-signal thread id
  const int bc = blockIdx.x * 2 + sig;   // b*512 + c
  const int c = bc & 511, b = bc >> 9;
  float2* X = X2[sig];
  unsigned int* sigb = (unsigned int*)(vTb + (size_t)bc * 4096);
  for (int m = tid; m < 1024; m += 512) { Wl[PHYS(m)] = Wg[m]; S[m] = Sg[m]; }
  fwd_stage1_bf16(X, sigb, t);
  stage_r8<false, 8>(X, Wl, t);
  stage_r8<false, 64>(X, Wl, t);
  stage_r4<false>(X, Wl, t);
  const float scale = 1.0f / 2048.0f;
#pragma unroll 1
  for (int k = 0; k < 3; ++k) {
    const float2* H = Hf + (size_t)(k * 512 + c) * HSTR;
    for (int kk = t; kk < 1024; kk += 256) {
      if (kk == 0) {
        float h0x = H[0].x, hMx = H[2048].x;
        float2 hq = H[1024];
        float a1r = 0.5f * (h0x + hMx), a1w = 0.5f * (h0x - hMx);
        float2 Z0 = X[PHYS(0)], Zq = X[PHYS(1024)];
        X[PHYS(0)]    = make_float2(a1r * Z0.x + a1w * Z0.y, a1r * Z0.y + a1w * Z0.x);
        X[PHYS(1024)] = make_float2(hq.x * Zq.x + hq.y * Zq.y, hq.x * Zq.y - hq.y * Zq.x);
      } else {
        float2 hk = H[kk], hm = H[2048 - kk];
        float cs = S[kk].x, sn = S[kk].y;
        float oms = 0.5f * (1.f - sn), ops = 0.5f * (1.f + sn), c2h = 0.5f * cs;
        float d1x = hk.x - hm.x, d1y = hk.y + hm.y;
        float a1x = oms * hk.x + ops * hm.x, a1y = oms * hk.y - ops * hm.y;
        float b1x = -c2h * d1y, b1y = c2h * d1x;
        float a2x = oms * hm.x + ops * hk.x, a2y = oms * hm.y - ops * hk.y;
        float b2x = c2h * d1y, b2y = c2h * d1x;
        float2 Zk = X[PHYS(kk)], Zm = X[PHYS(2048 - kk)];
        X[PHYS(kk)] = make_float2(a1x * Zk.x - a1y * Zk.y + b1x * Zm.x + b1y * Zm.y,
                                  a1x * Zk.y + a1y * Zk.x - b1x * Zm.y + b1y * Zm.x);
        X[PHYS(2048 - kk)] = make_float2(a2x * Zm.x - a2y * Zm.y + b2x * Zk.x + b2y * Zk.y,
                                         a2x * Zm.y + a2y * Zm.x - b2x * Zk.y + b2y * Zk.x);
      }
    }
    __syncthreads();
    stage_r8<true, 1>(X, Wl, t);
    stage_r8<true, 8>(X, Wl, t);
    stage_r8<true, 64>(X, Wl, t);
    const unsigned int* xnb = (const unsigned int*)(projsT + ((size_t)(k * 4 + b) * 512 + c) * 4096);
    if (k < 2) {
      stage_r4<true>(X, Wl, t);
      fwd_stage1_gated(X, xnb, scale, t);
      stage_r8<false, 8>(X, Wl, t);
      stage_r8<false, 64>(X, Wl, t);
      stage_r4<false>(X, Wl, t);
    } else {
      stage_r4_store(X, Wl, xnb, scale, sigb, t);
    }
  }
}

// ---------------- output GEMM (LDS-staged, bf16 v) ----------------

__launch_bounds__(256, 2)
__global__ void out_gemm(const ushortT* __restrict__ vTb, const float* __restrict__ oW,
                         const float* __restrict__ ob, float* __restrict__ out) {
  __shared__ float vs[64][68];
  __shared__ float ows[64][36];
  const int l0 = blockIdx.x * 64;
  const int b = l0 >> 12;
  const int tid = threadIdx.x;
  const int l = tid & 63;
  const int og = (tid >> 6) * 8;
  float acc[8] = {};
  const ushortT* vb = vTb + (size_t)b * 2097152 + (l0 & 4095);
  const int cs = tid >> 2;
  const int lq = (tid & 3) * 16;
  const int oq = (tid & 3) * 8;
#pragma unroll 1
  for (int cc = 0; cc < 512; cc += 64) {
#pragma unroll
    for (int i = 0; i < 2; ++i) {
      ushort8v u8 = *(const ushort8v*)(vb + (size_t)(cc + cs) * 4096 + lq + i * 8);
#pragma unroll
      for (int j = 0; j < 8; ++j) vs[cs][lq + i * 8 + j] = bf2f(u8[j]);
    }
    *(f32x4*)(&ows[cs][oq])     = *(const f32x4*)(oW + (cc + cs) * 32 + oq);
    *(f32x4*)(&ows[cs][oq + 4]) = *(const f32x4*)(oW + (cc + cs) * 32 + oq + 4);
    __syncthreads();
#pragma unroll 8
    for (int c3 = 0; c3 < 64; ++c3) {
      float v = vs[c3][l];
#pragma unroll
      for (int j = 0; j < 8; ++j)
        acc[j] = fmaf(v, ows[c3][og + j], acc[j]);
    }
    __syncthreads();
  }
  float* op = out + (size_t)(l0 + l) * 32 + og;
  f32x4 r0, r1;
  r0[0] = acc[0] + ob[og];     r0[1] = acc[1] + ob[og + 1];
  r0[2] = acc[2] + ob[og + 2]; r0[3] = acc[3] + ob[og + 3];
  r1[0] = acc[4] + ob[og + 4]; r1[1] = acc[5] + ob[og + 5];
  r1[2] = acc[6] + ob[og + 6]; r1[3] = acc[7] + ob[og + 7];
  *(f32x4*)op = r0;
  *(f32x4*)(op + 4) = r1;
}

// ---------------- diagnostics ----------------

__global__ void ws_sentinel(float* __restrict__ out) {
  if (threadIdx.x == 0) out[0] = -31337.0f;
}

// ---------------- launch ----------------

extern "C" void kernel_launch(void* const* d_in, const int* in_sizes, int n_in,
                              void* d_out, int out_size, void* d_ws, size_t ws_size,
                              hipStream_t stream) {
  (void)in_sizes; (void)n_in; (void)out_size;
  const float* u  = (const float*)d_in[0];
  const float* pW = (const float*)d_in[1];
  const float* pb = (const float*)d_in[2];
  const float* cW = (const float*)d_in[3];
  const float* cb = (const float*)d_in[4];
  const float* fW = (const float*)d_in[5];
  const float* fb = (const float*)d_in[6];
  const float* oW = (const float*)d_in[7];
  const float* ob = (const float*)d_in[8];
  float* out = (float*)d_out;

  char* ws = (char*)d_ws;
  // persistent region
  ushortT* Upad   = (ushortT*)(ws);                    // 16,785,408
  ushortT* cWf    = (ushortT*)(ws + 16785408);         //  6,291,456
  float*   biasC  = (float*)  (ws + 23076864);         //      8,192
  float*   pbC0   = (float*)  (ws + 23085056);         //      8,192
  float*   pbC2   = (float*)  (ws + 23093248);         //      8,192
  float2*  Wg     = (float2*) (ws + 23101440);         //     16,384
  float2*  Sg     = (float2*) (ws + 23117824);         //      8,192
  float2*  Hf     = (float2*) (ws + 23126016);         // 25,264,128 (1536 x HSTR c64)
  ushortT* vTb    = (ushortT*)(ws + 48390144);         // 16,777,216 (4x512x4096 bf16)
  ushortT* projsT = (ushortT*)(ws + 65167360);         // 50,331,648
  const size_t total = 115499008;                      // 110.2 MiB
  // scratch overlay on [vTb, end) — all dead before gemm_conv8 writes vTb/projsT
  char* S = (char*)vTb;
  ushortT* Wt     = (ushortT*)(S);                     // 25,165,824
  ushortT* pW_bf  = (ushortT*)(S + 25165824);          //  2,097,152
  float*   hT     = (float*)  (S + 27262976);          // 25,165,824 -> ends 52,428,800 (< 67,108,864)

  if (total > ws_size) {
    ws_sentinel<<<1, 64, 0, stream>>>(out);
    return;
  }

  prep_cwt<<<11292, 256, 0, stream>>>(u, Upad, pW, pW_bf, Wg, Sg, cW, pb, cb, Wt, biasC, pbC0, pbC2);
  gemm_fold<<<dim3(32, 4, 3), 256, 0, stream>>>(Wt, pW_bf, cWf);        // Wt,pW_bf dead after
  h_kernel<<<dim3(64, 12), 256, 0, stream>>>(fW, fb, hT);
  fft_filter_r<<<1536, 256, 0, stream>>>(hT, Wg, Hf);                   // hT dead after
  gemm_conv8<<<512, 512, 0, stream>>>(Upad, cWf, biasC, pbC0, pbC2, vTb, projsT);
  fft_conv3<<<1024, 512, 0, stream>>>(vTb, projsT, Hf, Wg, Sg);
  out_gemm<<<256, 256, 0, stream>>>(vTb, oW, ob, out);
}

// Round 16
// 312.127 us; speedup vs baseline: 1.0897x; 1.0897x over previous
//
#include <hip/hip_runtime.h>

typedef __attribute__((ext_vector_type(8))) short short8;
typedef __attribute__((ext_vector_type(4))) float f32x4;
typedef __attribute__((ext_vector_type(4))) unsigned short ushort4v;
typedef __attribute__((ext_vector_type(8))) unsigned short ushort8v;
typedef unsigned short ushortT;

#define PADROWS 4098
#define HSTR 2056
#define PI_F 3.14159265358979323f
#define PHYS(i) ((i) ^ (((i) >> 4) & 15))

__device__ __forceinline__ ushortT f2bf(float f) {
  union { float f; unsigned int u; } v; v.f = f;
  unsigned int r = (v.u + 0x7FFFu + ((v.u >> 16) & 1u)) >> 16;
  return (ushortT)r;
}
__device__ __forceinline__ float bf2f(ushortT b) {
  union { unsigned int u; float f; } v; v.u = ((unsigned int)b) << 16;
  return v.f;
}

__device__ __forceinline__ void gl2lds16(const void* g, void* l) {
  __builtin_amdgcn_global_load_lds((const __attribute__((address_space(1))) void*)g,
                                   (__attribute__((address_space(3))) void*)l, 16, 0, 0);
}

// ---------------- fused prep: u->Upad(+pad), pW cast, tables, cW->Wt + pbC ----------------

__global__ void prep_cwt(const float* __restrict__ u, ushortT* __restrict__ up,
                         const float* __restrict__ pW, ushortT* __restrict__ pW_bf,
                         float2* __restrict__ Wg, float2* __restrict__ Sg,
                         const float* __restrict__ cW, const float* __restrict__ pb,
                         const float* __restrict__ cb, ushortT* __restrict__ Wt,
                         float* __restrict__ biasC, float* __restrict__ pbC0,
                         float* __restrict__ pbC2) {
  int blk = blockIdx.x;
  int tid = threadIdx.x;
  if (blk < 8192) {
    size_t idx = (size_t)blk * 256 + tid;
    f32x4 v = *(const f32x4*)(u + idx * 4);
    ushort4v r;
    r[0] = f2bf(v[0]); r[1] = f2bf(v[1]); r[2] = f2bf(v[2]); r[3] = f2bf(v[3]);
    size_t g = idx * 4;
    int col = (int)(g & 511);
    int l = (int)(g >> 9);
    int b = l >> 12;
    *(ushort4v*)(up + ((size_t)b * PADROWS + (l & 4095) + 1) * 512 + col) = r;
    return;
  }
  if (blk < 8208) {
    int idx = (blk - 8192) * 256 + tid;   // 4096
    int col = idx & 511;
    int r = (idx >> 9) & 1;
    int b = idx >> 10;
    up[((size_t)b * PADROWS + (r ? 4097 : 0)) * 512 + col] = 0;
    return;
  }
  if (blk < 9232) {
    size_t idx = (size_t)(blk - 8208) * 256 + tid;
    f32x4 v = *(const f32x4*)(pW + idx * 4);
    ushort4v r;
    r[0] = f2bf(v[0]); r[1] = f2bf(v[1]); r[2] = f2bf(v[2]); r[3] = f2bf(v[3]);
    *(ushort4v*)(pW_bf + idx * 4) = r;
    return;
  }
  if (blk < 9244) {
    int m = (blk - 9232) * 256 + tid;  // 3072
    float sn, cs;
    if (m < 2048) {
      sincosf(-2.0f * PI_F * (float)m / 2048.0f, &sn, &cs);
      Wg[m] = make_float2(cs, sn);
    } else {
      int k = m - 2048;
      sincosf(PI_F * (float)k / 2048.0f, &sn, &cs);
      Sg[k] = make_float2(cs, sn);
    }
    return;
  }
  // cW pass: o = blk - 9244 (2048 blocks)
  int o = blk - 9244;
  float s0 = 0.f, s1 = 0.f, s2 = 0.f;
  const float* base = cW + (size_t)o * 6144;
  for (int i = tid; i < 2048; i += 256) {
    float w0 = base[i * 3], w1 = base[i * 3 + 1], w2 = base[i * 3 + 2];
    size_t oi = (size_t)o * 2048 + i;
    Wt[oi]           = f2bf(w0);
    Wt[oi + 4194304] = f2bf(w1);
    Wt[oi + 8388608] = f2bf(w2);
    float p = pb[i];
    s0 = fmaf(p, w0, s0);
    s1 = fmaf(p, w1, s1);
    s2 = fmaf(p, w2, s2);
  }
#pragma unroll
  for (int off = 32; off >= 1; off >>= 1) {
    s0 += __shfl_down(s0, off);
    s1 += __shfl_down(s1, off);
    s2 += __shfl_down(s2, off);
  }
  __shared__ float red[4][3];
  if ((tid & 63) == 0) { red[tid >> 6][0] = s0; red[tid >> 6][1] = s1; red[tid >> 6][2] = s2; }
  __syncthreads();
  if (tid == 0) {
    float a0 = red[0][0] + red[1][0] + red[2][0] + red[3][0];
    float a1 = red[0][1] + red[1][1] + red[2][1] + red[3][1];
    float a2 = red[0][2] + red[1][2] + red[2][2] + red[3][2];
    biasC[o] = cb[o] + a0 + a1 + a2;
    pbC0[o] = a0;
    pbC2[o] = a2;
  }
}

// ---------------- fold GEMM: cWf[h][o][j] = sum_i Wt[h][o][i] * pW[j][i] ----------------
// 64(o) x 128(j) tile, grid (32,4,3) = 384 blocks, 24 KiB LDS.

__launch_bounds__(256, 4)
__global__ void gemm_fold(const ushortT* __restrict__ Wt, const ushortT* __restrict__ pW_bf,
                          ushortT* __restrict__ cWf) {
  __shared__ alignas(16) ushortT As[64 * 64];    // 8 KiB
  __shared__ alignas(16) ushortT Bs[128 * 64];   // 16 KiB
  const int tid = threadIdx.x;
  const int lane = tid & 63, w = tid >> 6;
  const int wm = w >> 1, wn = w & 1;
  const int tm = blockIdx.x, tn = blockIdx.y, h = blockIdx.z;
  const ushortT* A = Wt + (size_t)h * 4194304;
  f32x4 acc[2][4] = {};
#pragma unroll 1
  for (int kt = 0; kt < 32; ++kt) {
    const int i0 = kt * 64;
#pragma unroll
    for (int i = 0; i < 2; ++i) {
      int ldsoff = (i * 4 + w) * 1024;
      int m = ((i * 4 + w) << 3) + (lane >> 3);   // 0..63
      int col = (lane & 7) * 8;
      gl2lds16(A + (size_t)(tm * 64 + m) * 2048 + i0 + col, (char*)As + ldsoff);
    }
#pragma unroll
    for (int i = 0; i < 4; ++i) {
      int ldsoff = (i * 4 + w) * 1024;
      int m = ((i * 4 + w) << 3) + (lane >> 3);   // 0..127
      int col = (lane & 7) * 8;
      gl2lds16(pW_bf + (size_t)(tn * 128 + m) * 2048 + i0 + col, (char*)Bs + ldsoff);
    }
    __syncthreads();
#pragma unroll
    for (int ks = 0; ks < 2; ++ks) {
      short8 av[2], bv[4];
#pragma unroll
      for (int mi = 0; mi < 2; ++mi) {
        int row = wm * 32 + mi * 16 + (lane & 15);
        av[mi] = *(const short8*)(As + row * 64 + (ks * 4 + (lane >> 4)) * 8);
      }
#pragma unroll
      for (int ni = 0; ni < 4; ++ni) {
        int row = wn * 64 + ni * 16 + (lane & 15);
        bv[ni] = *(const short8*)(Bs + row * 64 + (ks * 4 + (lane >> 4)) * 8);
      }
#pragma unroll
      for (int mi = 0; mi < 2; ++mi)
#pragma unroll
        for (int ni = 0; ni < 4; ++ni)
          acc[mi][ni] = __builtin_amdgcn_mfma_f32_16x16x32_bf16(av[mi], bv[ni], acc[mi][ni], 0, 0, 0);
    }
    __syncthreads();
  }
#pragma unroll
  for (int mi = 0; mi < 2; ++mi)
#pragma unroll
    for (int ni = 0; ni < 4; ++ni) {
      int jc = tn * 128 + wn * 64 + ni * 16 + (lane & 15);
#pragma unroll
      for (int j = 0; j < 4; ++j) {
        int o = tm * 64 + wm * 32 + mi * 16 + (lane >> 4) * 4 + j;
        cWf[((size_t)h * 2048 + o) * 512 + jc] = f2bf(acc[mi][ni][j]);
      }
    }
}

// ---------------- conv GEMM: 256x256, BK=64, 8-phase SINGLE-BARRIER pipeline ----------------

__launch_bounds__(512, 2)
__global__ void gemm_conv8(const ushortT* __restrict__ Upad, const ushortT* __restrict__ cWf,
                           const float* __restrict__ biasC, const float* __restrict__ pbC0,
                           const float* __restrict__ pbC2, ushortT* __restrict__ vTb,
                           ushortT* __restrict__ projsT) {
  __shared__ ushortT lds[2][2][16384];
  const int tid = threadIdx.x;
  const int lane = tid & 63, w = tid >> 6;
  const int wm = w >> 2, wn = w & 3;
  int raw = blockIdx.x;
  int wg  = (raw & 7) * 64 + (raw >> 3);
  const int o0 = (wg >> 6) << 8;
  const int nt = wg & 63;
  const int b  = nt >> 4;
  const int l0 = (nt & 15) << 8;

  f32x4 acc[8][4] = {};
  short8 xf[4][2];

  const int sm = tid >> 3;
  const int sw1 = ((tid & 7) ^ (sm & 7)) << 3;

  auto stageW = [&](int slot, int half, int t) {
    int q = (t * 21846) >> 16, h = t - 3 * q, j0 = q << 6;
    size_t grow = (size_t)(h * 2048 + o0 + half * 128 + sm);
    char* dst = (char*)&lds[slot][0][0] + half * 16384 + w * 1024;
    gl2lds16(cWf + grow * 512 + j0 + sw1, dst);
    gl2lds16(cWf + (grow + 64) * 512 + j0 + sw1, dst + 8192);
  };
  auto stageX = [&](int slot, int half, int t) {
    int q = (t * 21846) >> 16, h = t - 3 * q, j0 = q << 6;
    size_t grow = (size_t)b * PADROWS + l0 + h + half * 128 + sm;
    char* dst = (char*)&lds[slot][1][0] + half * 16384 + w * 1024;
    gl2lds16(Upad + grow * 512 + j0 + sw1, dst);
    gl2lds16(Upad + (grow + 64) * 512 + j0 + sw1, dst + 8192);
  };
  auto ldsW = [&](int slot, int mi, int ks) -> short8 {
    int row = wm * 128 + mi * 16 + (lane & 15);
    int ch = (ks * 4 + (lane >> 4)) ^ (row & 7);
    return *(const short8*)&lds[slot][0][row * 64 + ch * 8];
  };
  auto ldsX = [&](int slot, int ni, int ks) -> short8 {
    int row = wn * 64 + ni * 16 + (lane & 15);
    int ch = (ks * 4 + (lane >> 4)) ^ (row & 7);
    return *(const short8*)&lds[slot][1][row * 64 + ch * 8];
  };

  stageW(0, 0, 0); stageW(0, 1, 0);
  stageX(0, 0, 0); stageX(0, 1, 0);
  stageX(1, 0, 1); stageX(1, 1, 1);
  asm volatile("s_waitcnt vmcnt(0)" ::: "memory");
  __builtin_amdgcn_s_barrier();

#define PHASE(slot, q, STAGECODE, VMCODE)                                                                    \
  {                                                                                                          \
    short8 w0k0 = ldsW(slot, 2*(q), 0), w0k1 = ldsW(slot, 2*(q), 1);                                         \
    short8 w1k0 = ldsW(slot, 2*(q)+1, 0), w1k1 = ldsW(slot, 2*(q)+1, 1);                                     \
    if ((q) == 0) {                                                                                          \
      _Pragma("unroll")                                                                                      \
      for (int ni = 0; ni < 4; ++ni) {                                                                       \
        xf[ni][0] = ldsX(slot, ni, 0);                                                                       \
        xf[ni][1] = ldsX(slot, ni, 1);                                                                       \
      }                                                                                                      \
    }                                                                                                        \
    STAGECODE;                                                                                               \
    VMCODE;                                                                                                  \
    __builtin_amdgcn_s_barrier();                                                                            \
    asm volatile("s_waitcnt lgkmcnt(0)" ::: "memory");                                                       \
    __builtin_amdgcn_sched_barrier(0);                                                                       \
    __builtin_amdgcn_s_setprio(1);                                                                           \
    _Pragma("unroll")                                                                                        \
    for (int ni = 0; ni < 4; ++ni) {                                                                         \
      acc[2*(q)][ni]   = __builtin_amdgcn_mfma_f32_16x16x32_bf16(w0k0, xf[ni][0], acc[2*(q)][ni], 0, 0, 0);  \
      acc[2*(q)][ni]   = __builtin_amdgcn_mfma_f32_16x16x32_bf16(w0k1, xf[ni][1], acc[2*(q)][ni], 0, 0, 0);  \
      acc[2*(q)+1][ni] = __builtin_amdgcn_mfma_f32_16x16x32_bf16(w1k0, xf[ni][0], acc[2*(q)+1][ni], 0, 0, 0);\
      acc[2*(q)+1][ni] = __builtin_amdgcn_mfma_f32_16x16x32_bf16(w1k1, xf[ni][1], acc[2*(q)+1][ni], 0, 0, 0);\
    }                                                                                                        \
    __builtin_amdgcn_s_setprio(0);                                                                           \
  }

#pragma unroll 1
  for (int it = 0; it < 11; ++it) {
    const int t0 = 2 * it;
    PHASE(0, 0, , );
    PHASE(0, 1, stageW(1, 0, t0 + 1), );
    PHASE(0, 2, stageW(1, 1, t0 + 1); stageX(0, 0, t0 + 2), );
    PHASE(0, 3, stageX(0, 1, t0 + 2), asm volatile("s_waitcnt vmcnt(4)" ::: "memory"));
    PHASE(1, 0, , );
    PHASE(1, 1, stageW(0, 0, t0 + 2), );
    PHASE(1, 2, stageW(0, 1, t0 + 2); stageX(1, 0, t0 + 3), );
    PHASE(1, 3, stageX(1, 1, t0 + 3), asm volatile("s_waitcnt vmcnt(4)" ::: "memory"));
  }
  // peel: t=22 (slot0), t=23 (slot1); only W(23) still needs staging
  PHASE(0, 0, , );
  PHASE(0, 1, stageW(1, 0, 23), );
  PHASE(0, 2, stageW(1, 1, 23), );
  PHASE(0, 3, , asm volatile("s_waitcnt vmcnt(0)" ::: "memory"));
  PHASE(1, 0, , );
  PHASE(1, 1, , );
  PHASE(1, 2, , );
  PHASE(1, 3, , );
#undef PHASE

  const int r4 = (lane >> 4) * 4;
  const int lbase = l0 + wn * 64 + (lane & 15);
  if (o0 < 512) {
#pragma unroll
    for (int mi = 0; mi < 8; ++mi)
#pragma unroll
      for (int ni = 0; ni < 4; ++ni) {
        int l = lbase + ni * 16;
#pragma unroll
        for (int j = 0; j < 4; ++j) {
          int o = o0 + wm * 128 + mi * 16 + r4 + j;
          float val = acc[mi][ni][j] + biasC[o];
          if (l == 0) val -= pbC0[o];
          if (l == 4095) val -= pbC2[o];
          vTb[((size_t)b * 512 + o) * 4096 + l] = f2bf(val);
        }
      }
  } else {
#pragma unroll
    for (int mi = 0; mi < 8; ++mi)
#pragma unroll
      for (int ni = 0; ni < 4; ++ni) {
        int l = lbase + ni * 16;
#pragma unroll
        for (int j = 0; j < 4; ++j) {
          int o = o0 + wm * 128 + mi * 16 + r4 + j;
          float val = acc[mi][ni][j] + biasC[o];
          if (l == 0) val -= pbC0[o];
          if (l == 4095) val -= pbC2[o];
          int oc = o - 512;
          projsT[((size_t)((oc >> 9) * 4 + b) * 512 + (oc & 511)) * 4096 + l] = f2bf(val);
        }
      }
  }
}

// ---------------- filter GEMM: hT[ch][l] = (t @ fW + fb)*window, PE computed in-kernel ----------------

__launch_bounds__(256, 1)
__global__ void h_kernel(const float* __restrict__ fW, const float* __restrict__ fb,
                         float* __restrict__ hT) {
  __shared__ float tTs[128][64];
  __shared__ float fWs[128][128];
  const int l0 = blockIdx.x * 64;
  const int c0 = blockIdx.y * 128;
  const int tid = threadIdx.x;
  for (int r = tid; r < 4096; r += 256) {
    int d2 = r >> 6, li = r & 63;
    float dv = expf(-9.210340371976184f * (float)(2 * d2) / 128.0f);
    float ang = (float)(l0 + li) * dv;
    tTs[2 * d2][li] = sinf(ang);
    tTs[2 * d2 + 1][li] = cosf(ang);
  }
  {
    int cq = (tid & 31) * 4;
    int dr = tid >> 5;
#pragma unroll
    for (int d = dr; d < 128; d += 8)
      *(f32x4*)(&fWs[d][cq]) = *(const f32x4*)(fW + (size_t)d * 1536 + c0 + cq);
  }
  __syncthreads();
  const int lgrp = tid & 15;
  const int cg = tid >> 4;
  float acc[8][4] = {};
#pragma unroll 4
  for (int d = 0; d < 128; ++d) {
    f32x4 tv = *(const f32x4*)(&tTs[d][lgrp * 4]);
#pragma unroll
    for (int j = 0; j < 8; ++j) {
      float wv = fWs[d][cg + 16 * j];
      acc[j][0] = fmaf(tv[0], wv, acc[j][0]);
      acc[j][1] = fmaf(tv[1], wv, acc[j][1]);
      acc[j][2] = fmaf(tv[2], wv, acc[j][2]);
      acc[j][3] = fmaf(tv[3], wv, acc[j][3]);
    }
  }
  f32x4 wl;
#pragma unroll
  for (int j = 0; j < 4; ++j) {
    int l = l0 + lgrp * 4 + j;
    wl[j] = 0.5f * (1.0f - cosf(6.283185307179586f * (float)l / 4095.0f));
  }
#pragma unroll
  for (int j = 0; j < 8; ++j) {
    int ch = c0 + cg + 16 * j;
    float fbv = fb[ch];
    f32x4 r;
    r[0] = (acc[j][0] + fbv) * wl[0];
    r[1] = (acc[j][1] + fbv) * wl[1];
    r[2] = (acc[j][2] + fbv) * wl[2];
    r[3] = (acc[j][3] + fbv) * wl[3];
    *(f32x4*)(hT + (size_t)ch * 4096 + l0 + lgrp * 4) = r;
  }
}

// ---------------- radix-8 Stockham FFT, N=2048 complex, in-place in LDS ----------------
// Twiddle table halved: Wl[1024] holds exp(-2*pi*i*m/2048) for m<1024; W[m+1024] = -W[m].

__device__ __forceinline__ float2 cadd(float2 a, float2 b){ return make_float2(a.x+b.x, a.y+b.y); }
__device__ __forceinline__ float2 csub(float2 a, float2 b){ return make_float2(a.x-b.x, a.y-b.y); }
__device__ __forceinline__ float2 cmulp(float2 a, float2 b){
  return make_float2(a.x*b.x - a.y*b.y, a.x*b.y + a.y*b.x);
}
__device__ __forceinline__ float2 ldw(const float2* __restrict__ Wl, int m) {
  float2 w = Wl[PHYS(m & 1023)];
  unsigned int neg = (unsigned int)(m & 1024) << 21;   // 0x80000000 when m>=1024
  w.x = __uint_as_float(__float_as_uint(w.x) ^ neg);
  w.y = __uint_as_float(__float_as_uint(w.y) ^ neg);
  return w;
}
template<bool INV>
__device__ __forceinline__ float2 tw_mul(float2 a, float2 w) {
  return INV ? make_float2(fmaf(a.x, w.x,  a.y*w.y), fmaf(a.y, w.x, -a.x*w.y))
             : make_float2(fmaf(a.x, w.x, -a.y*w.y), fmaf(a.x, w.y,  a.y*w.x));
}
template<bool INV>
__device__ __forceinline__ float2 rot(float2 z) {
  return INV ? make_float2(-z.y, z.x) : make_float2(z.y, -z.x);
}

template<bool INV>
__device__ __forceinline__ void bfly8(const float2 v[8], float2 o[8]) {
  const float C7 = 0.70710678118654752f;
  float2 a0 = cadd(v[0], v[4]), a1 = csub(v[0], v[4]);
  float2 a2 = cadd(v[2], v[6]), a3 = rot<INV>(csub(v[2], v[6]));
  float2 E0 = cadd(a0, a2), E1 = cadd(a1, a3), E2 = csub(a0, a2), E3 = csub(a1, a3);
  float2 b0 = cadd(v[1], v[5]), b1 = csub(v[1], v[5]);
  float2 b2 = cadd(v[3], v[7]), b3 = rot<INV>(csub(v[3], v[7]));
  float2 O0 = cadd(b0, b2), O1 = cadd(b1, b3), O2 = csub(b0, b2), O3 = csub(b1, b3);
  O1 = cmulp(O1, INV ? make_float2(C7, C7) : make_float2(C7, -C7));
  O2 = rot<INV>(O2);
  O3 = cmulp(O3, INV ? make_float2(-C7, C7) : make_float2(-C7, -C7));
  o[0] = cadd(E0, O0); o[1] = cadd(E1, O1); o[2] = cadd(E2, O2); o[3] = cadd(E3, O3);
  o[4] = csub(E0, O0); o[5] = csub(E1, O1); o[6] = csub(E2, O2); o[7] = csub(E3, O3);
}

template<bool INV, int NS>
__device__ __forceinline__ void stage_r8(float2* X, const float2* Wl, int t) {
  float2 v[8];
#pragma unroll
  for (int r = 0; r < 8; ++r) v[r] = X[PHYS(t + 256 * r)];
  if (NS > 1) {
    const int jm = (t & (NS - 1)) * (256 / NS);
#pragma unroll
    for (int r = 1; r < 8; ++r) v[r] = tw_mul<INV>(v[r], ldw(Wl, r * jm));
  }
  float2 o[8];
  bfly8<INV>(v, o);
  __syncthreads();
  const int base = (t / NS) * (8 * NS) + (t % NS);
#pragma unroll
  for (int i = 0; i < 8; ++i) X[PHYS(base + i * NS)] = o[i];
  __syncthreads();
}

template<bool INV>
__device__ __forceinline__ void stage_r4(float2* X, const float2* Wl, int t) {
#pragma unroll
  for (int jj = 0; jj < 2; ++jj) {
    const int j = t + jj * 256;
    float2 v0 = X[PHYS(j)], v1 = X[PHYS(j + 512)], v2 = X[PHYS(j + 1024)], v3 = X[PHYS(j + 1536)];
    v1 = tw_mul<INV>(v1, ldw(Wl, j));
    v2 = tw_mul<INV>(v2, ldw(Wl, 2 * j));
    v3 = tw_mul<INV>(v3, ldw(Wl, 3 * j));
    float2 a0 = cadd(v0, v2), a1 = csub(v0, v2), a2 = cadd(v1, v3), a3 = rot<INV>(csub(v1, v3));
    X[PHYS(j)]        = cadd(a0, a2);
    X[PHYS(j + 512)]  = cadd(a1, a3);
    X[PHYS(j + 1024)] = csub(a0, a2);
    X[PHYS(j + 1536)] = csub(a1, a3);
  }
  __syncthreads();
}

__device__ __forceinline__ void fwd_stage1_bf16(float2* X, const unsigned int* __restrict__ sigb, int t) {
  float2 v[8], o[8];
#pragma unroll
  for (int r = 0; r < 8; ++r) {
    unsigned int pr = sigb[t + 256 * r];
    v[r] = make_float2(bf2f((ushortT)(pr & 0xffffu)), bf2f((ushortT)(pr >> 16)));
  }
  bfly8<false>(v, o);
  const int base = t * 8;
#pragma unroll
  for (int i = 0; i < 8; ++i) X[PHYS(base + i)] = o[i];
  __syncthreads();
}

__device__ __forceinline__ void fwd_stage1_f32(float2* X, const float* __restrict__ sig, int t) {
  float2 v[8], o[8];
#pragma unroll
  for (int r = 0; r < 8; ++r) v[r] = *(const float2*)(sig + 2 * (t + 256 * r));
  bfly8<false>(v, o);
  const int base = t * 8;
#pragma unroll
  for (int i = 0; i < 8; ++i) X[PHYS(base + i)] = o[i];
  __syncthreads();
}

__device__ __forceinline__ void fwd_stage1_gated(float2* X, const unsigned int* __restrict__ xnb,
                                                 float scale, int t) {
  float2 v[8], o[8];
#pragma unroll
  for (int r = 0; r < 8; ++r) {
    const int m = t + 256 * r;
    unsigned int pr = xnb[m];
    float2 a = X[PHYS(m)];
    v[r] = make_float2(a.x * scale * bf2f((ushortT)(pr & 0xffffu)),
                       a.y * scale * bf2f((ushortT)(pr >> 16)));
  }
  bfly8<false>(v, o);
  __syncthreads();
  const int base = t * 8;
#pragma unroll
  for (int i = 0; i < 8; ++i) X[PHYS(base + i)] = o[i];
  __syncthreads();
}

__device__ __forceinline__ void stage_r4_store(const float2* X, const float2* Wl,
                                               const unsigned int* __restrict__ xnb,
                                               float scale, unsigned int* __restrict__ outb, int t) {
#pragma unroll
  for (int jj = 0; jj < 2; ++jj) {
    const int j = t + jj * 256;
    float2 v0 = X[PHYS(j)], v1 = X[PHYS(j + 512)], v2 = X[PHYS(j + 1024)], v3 = X[PHYS(j + 1536)];
    v1 = tw_mul<true>(v1, ldw(Wl, j));
    v2 = tw_mul<true>(v2, ldw(Wl, 2 * j));
    v3 = tw_mul<true>(v3, ldw(Wl, 3 * j));
    float2 a0 = cadd(v0, v2), a1 = csub(v0, v2), a2 = cadd(v1, v3), a3 = rot<true>(csub(v1, v3));
    float2 y[4] = { cadd(a0, a2), cadd(a1, a3), csub(a0, a2), csub(a1, a3) };
    const int idx[4] = { j, j + 512, j + 1024, j + 1536 };
#pragma unroll
    for (int q = 0; q < 4; ++q) {
      unsigned int pr = xnb[idx[q]];
      unsigned int lo = f2bf(y[q].x * scale * bf2f((ushortT)(pr & 0xffffu)));
      unsigned int hi = f2bf(y[q].y * scale * bf2f((ushortT)(pr >> 16)));
      outb[idx[q]] = lo | (hi << 16);
    }
  }
}

// filters: rfft of hT rows -> half-spectrum Hf[ch][0..2048]
__launch_bounds__(256, 4)
__global__ void fft_filter_r(const float* __restrict__ hT, const float2* __restrict__ Wg,
                             float2* __restrict__ Hf) {
  __shared__ float2 X[2048];
  __shared__ float2 Wl[1024];
  const int ch = blockIdx.x;
  const int tid = threadIdx.x;
  const float* sig = hT + (size_t)ch * 4096;
  for (int m = tid; m < 1024; m += 256) Wl[PHYS(m)] = Wg[m];
  fwd_stage1_f32(X, sig, tid);
  stage_r8<false, 8>(X, Wl, tid);
  stage_r8<false, 64>(X, Wl, tid);
  stage_r4<false>(X, Wl, tid);
  float2* o = Hf + (size_t)ch * HSTR;
  for (int kk = tid; kk < 1024; kk += 256) {
    if (kk == 0) {
      float2 z0 = X[PHYS(0)];
      o[0]    = make_float2(z0.x + z0.y, 0.f);
      o[2048] = make_float2(z0.x - z0.y, 0.f);
      float2 zq = X[PHYS(1024)];
      o[1024] = make_float2(zq.x, -zq.y);
    } else {
      float2 zk = X[PHYS(kk)], zm = X[PHYS(2048 - kk)];
      float2 E = make_float2(0.5f * (zk.x + zm.x), 0.5f * (zk.y - zm.y));
      float2 D = make_float2(0.5f * (zk.x - zm.x), 0.5f * (zk.y + zm.y));
      float2 O = make_float2(D.y, -D.x);
      float sn, cs;
      __sincosf(-PI_F * (float)kk * (1.0f / 2048.0f), &sn, &cs);
      float2 twO = make_float2(O.x * cs - O.y * sn, O.x * sn + O.y * cs);
      o[kk]        = make_float2(E.x + twO.x, E.y + twO.y);
      o[2048 - kk] = make_float2(E.x - twO.x, -(E.y - twO.y));
    }
  }
}

// all 3 Hyena orders fused; bf16 signal I/O; gates fused into FFT entry/exit stages
__launch_bounds__(256, 4)
__global__ void fft_conv3(ushortT* __restrict__ vTb, const ushortT* __restrict__ projsT,
                          const float2* __restrict__ Hf, const float2* __restrict__ Wg,
                          const float2* __restrict__ Sg) {
  __shared__ float2 X[2048];
  __shared__ float2 Wl[1024];
  __shared__ float2 S[1024];
  const int bc = blockIdx.x;   // b*512 + c
  const int c = bc & 511, b = bc >> 9;
  const int tid = threadIdx.x;
  unsigned int* sigb = (unsigned int*)(vTb + (size_t)bc * 4096);
  for (int m = tid; m < 1024; m += 256) { Wl[PHYS(m)] = Wg[m]; S[m] = Sg[m]; }
  fwd_stage1_bf16(X, sigb, tid);
  stage_r8<false, 8>(X, Wl, tid);
  stage_r8<false, 64>(X, Wl, tid);
  stage_r4<false>(X, Wl, tid);
  const float scale = 1.0f / 2048.0f;
#pragma unroll 1
  for (int k = 0; k < 3; ++k) {
    const float2* H = Hf + (size_t)(k * 512 + c) * HSTR;
    for (int kk = tid; kk < 1024; kk += 256) {
      if (kk == 0) {
        float h0x = H[0].x, hMx = H[2048].x;
        float2 hq = H[1024];
        float a1r = 0.5f * (h0x + hMx), a1w = 0.5f * (h0x - hMx);
        float2 Z0 = X[PHYS(0)], Zq = X[PHYS(1024)];
        X[PHYS(0)]    = make_float2(a1r * Z0.x + a1w * Z0.y, a1r * Z0.y + a1w * Z0.x);
        X[PHYS(1024)] = make_float2(hq.x * Zq.x + hq.y * Zq.y, hq.x * Zq.y - hq.y * Zq.x);
      } else {
        float2 hk = H[kk], hm = H[2048 - kk];
        float cs = S[kk].x, sn = S[kk].y;
        float oms = 0.5f * (1.f - sn), ops = 0.5f * (1.f + sn), c2h = 0.5f * cs;
        float d1x = hk.x - hm.x, d1y = hk.y + hm.y;
        float a1x = oms * hk.x + ops * hm.x, a1y = oms * hk.y - ops * hm.y;
        float b1x = -c2h * d1y, b1y = c2h * d1x;
        float a2x = oms * hm.x + ops * hk.x, a2y = oms * hm.y - ops * hk.y;
        float b2x = c2h * d1y, b2y = c2h * d1x;
        float2 Zk = X[PHYS(kk)], Zm = X[PHYS(2048 - kk)];
        X[PHYS(kk)] = make_float2(a1x * Zk.x - a1y * Zk.y + b1x * Zm.x + b1y * Zm.y,
                                  a1x * Zk.y + a1y * Zk.x - b1x * Zm.y + b1y * Zm.x);
        X[PHYS(2048 - kk)] = make_float2(a2x * Zm.x - a2y * Zm.y + b2x * Zk.x + b2y * Zk.y,
                                         a2x * Zm.y + a2y * Zm.x - b2x * Zk.y + b2y * Zk.x);
      }
    }
    __syncthreads();
    stage_r8<true, 1>(X, Wl, tid);
    stage_r8<true, 8>(X, Wl, tid);
    stage_r8<true, 64>(X, Wl, tid);
    const unsigned int* xnb = (const unsigned int*)(projsT + ((size_t)(k * 4 + b) * 512 + c) * 4096);
    if (k < 2) {
      stage_r4<true>(X, Wl, tid);
      fwd_stage1_gated(X, xnb, scale, tid);
      stage_r8<false, 8>(X, Wl, tid);
      stage_r8<false, 64>(X, Wl, tid);
      stage_r4<false>(X, Wl, tid);
    } else {
      stage_r4_store(X, Wl, xnb, scale, sigb, tid);
    }
  }
}

// ---------------- output GEMM (LDS-staged, bf16 v) ----------------

__launch_bounds__(256, 2)
__global__ void out_gemm(const ushortT* __restrict__ vTb, const float* __restrict__ oW,
                         const float* __restrict__ ob, float* __restrict__ out) {
  __shared__ float vs[64][68];
  __shared__ float ows[64][36];
  const int l0 = blockIdx.x * 64;
  const int b = l0 >> 12;
  const int tid = threadIdx.x;
  const int l = tid & 63;
  const int og = (tid >> 6) * 8;
  float acc[8] = {};
  const ushortT* vb = vTb + (size_t)b * 2097152 + (l0 & 4095);
  const int cs = tid >> 2;
  const int lq = (tid & 3) * 16;
  const int oq = (tid & 3) * 8;
#pragma unroll 1
  for (int cc = 0; cc < 512; cc += 64) {
#pragma unroll
    for (int i = 0; i < 2; ++i) {
      ushort8v u8 = *(const ushort8v*)(vb + (size_t)(cc + cs) * 4096 + lq + i * 8);
#pragma unroll
      for (int j = 0; j < 8; ++j) vs[cs][lq + i * 8 + j] = bf2f(u8[j]);
    }
    *(f32x4*)(&ows[cs][oq])     = *(const f32x4*)(oW + (cc + cs) * 32 + oq);
    *(f32x4*)(&ows[cs][oq + 4]) = *(const f32x4*)(oW + (cc + cs) * 32 + oq + 4);
    __syncthreads();
#pragma unroll 8
    for (int c3 = 0; c3 < 64; ++c3) {
      float v = vs[c3][l];
#pragma unroll
      for (int j = 0; j < 8; ++j)
        acc[j] = fmaf(v, ows[c3][og + j], acc[j]);
    }
    __syncthreads();
  }
  float* op = out + (size_t)(l0 + l) * 32 + og;
  f32x4 r0, r1;
  r0[0] = acc[0] + ob[og];     r0[1] = acc[1] + ob[og + 1];
  r0[2] = acc[2] + ob[og + 2]; r0[3] = acc[3] + ob[og + 3];
  r1[0] = acc[4] + ob[og + 4]; r1[1] = acc[5] + ob[og + 5];
  r1[2] = acc[6] + ob[og + 6]; r1[3] = acc[7] + ob[og + 7];
  *(f32x4*)op = r0;
  *(f32x4*)(op + 4) = r1;
}

// ---------------- diagnostics ----------------

__global__ void ws_sentinel(float* __restrict__ out) {
  if (threadIdx.x == 0) out[0] = -31337.0f;
}

// ---------------- launch ----------------

extern "C" void kernel_launch(void* const* d_in, const int* in_sizes, int n_in,
                              void* d_out, int out_size, void* d_ws, size_t ws_size,
                              hipStream_t stream) {
  (void)in_sizes; (void)n_in; (void)out_size;
  const float* u  = (const float*)d_in[0];
  const float* pW = (const float*)d_in[1];
  const float* pb = (const float*)d_in[2];
  const float* cW = (const float*)d_in[3];
  const float* cb = (const float*)d_in[4];
  const float* fW = (const float*)d_in[5];
  const float* fb = (const float*)d_in[6];
  const float* oW = (const float*)d_in[7];
  const float* ob = (const float*)d_in[8];
  float* out = (float*)d_out;

  char* ws = (char*)d_ws;
  // persistent region
  ushortT* Upad   = (ushortT*)(ws);                    // 16,785,408
  ushortT* cWf    = (ushortT*)(ws + 16785408);         //  6,291,456
  float*   biasC  = (float*)  (ws + 23076864);         //      8,192
  float*   pbC0   = (float*)  (ws + 23085056);         //      8,192
  float*   pbC2   = (float*)  (ws + 23093248);         //      8,192
  float2*  Wg     = (float2*) (ws + 23101440);         //     16,384
  float2*  Sg     = (float2*) (ws + 23117824);         //      8,192
  float2*  Hf     = (float2*) (ws + 23126016);         // 25,264,128 (1536 x HSTR c64)
  ushortT* vTb    = (ushortT*)(ws + 48390144);         // 16,777,216 (4x512x4096 bf16)
  ushortT* projsT = (ushortT*)(ws + 65167360);         // 50,331,648
  const size_t total = 115499008;                      // 110.2 MiB
  // scratch overlay on [vTb, end) — all dead before gemm_conv8 writes vTb/projsT
  char* S = (char*)vTb;
  ushortT* Wt     = (ushortT*)(S);                     // 25,165,824
  ushortT* pW_bf  = (ushortT*)(S + 25165824);          //  2,097,152
  float*   hT     = (float*)  (S + 27262976);          // 25,165,824 -> ends 52,428,800 (< 67,108,864)

  if (total > ws_size) {
    ws_sentinel<<<1, 64, 0, stream>>>(out);
    return;
  }

  prep_cwt<<<11292, 256, 0, stream>>>(u, Upad, pW, pW_bf, Wg, Sg, cW, pb, cb, Wt, biasC, pbC0, pbC2);
  gemm_fold<<<dim3(32, 4, 3), 256, 0, stream>>>(Wt, pW_bf, cWf);        // Wt,pW_bf dead after
  h_kernel<<<dim3(64, 12), 256, 0, stream>>>(fW, fb, hT);
  fft_filter_r<<<1536, 256, 0, stream>>>(hT, Wg, Hf);                   // hT dead after
  gemm_conv8<<<512, 512, 0, stream>>>(Upad, cWf, biasC, pbC0, pbC2, vTb, projsT);
  fft_conv3<<<2048, 256, 0, stream>>>(vTb, projsT, Hf, Wg, Sg);
  out_gemm<<<256, 256, 0, stream>>>(vTb, oW, ob, out);
}